// Round 1
// 266.503 us; speedup vs baseline: 1.0324x; 1.0324x over previous
//
#include <hip/hip_runtime.h>

// SSIM (32,3,512,512) fp32, crop 4, 11x11 Gaussian sigma=1.5, per-batch mean.
//
// V3: 4-moment-field reformulation + 4 blocks/CU + wide Stage B.
//  Fields: r, d, s2=r^2+d^2, p2=(r+d)^2.  Then
//    2*E[rd] = conv(p2) - conv(s2);  var_r+var_d = conv(s2) - mr^2 - md^2.
//  => only 4 vertical+horizontal convolutions instead of 5 (-20% FMA, -20% LDS).
//  Stage A: vertical 11-tap from GLOBAL (coalesced float4, 2 rows x 4 cols per
//           task, 304 tasks) -> vs[4][32][76] (38.9 KB -> 4 blocks/CU).
//  Stage B: horizontal 11-tap, 1 row x 8 cols per thread: 5 ds_read_b128 per
//           field per thread (20 total vs 40 before), SSIM, block partial.

#define IMG   512
#define OUTD  494
#define CB    4
#define TW    64
#define TH    32
#define VSW   76           // 19 float4 groups; row = 304 B (16B-aligned)
#define C1F   6.5025f
#define C2F   58.5225f
#define NPIX  732108.0f    // 3*494*494
#define XBLK  8
#define YBLK  16
#define SLOTS 384          // XBLK*YBLK*3 partials per batch

__global__ __launch_bounds__(256, 4) void ssim_main(
        const float* __restrict__ raw, const float* __restrict__ dst,
        float* __restrict__ partial) {
    __shared__ float vs[4][TH][VSW];   // 38912 B -> 4 blocks/CU (was 51.2 KB -> 3)
    __shared__ float red[4];

    const int tid = threadIdx.x;
    const int bc  = blockIdx.z;
    const int b   = bc / 3;
    const int c3  = bc - b * 3;
    const int ty0 = blockIdx.y * TH;
    const int tx0 = blockIdx.x * TW;

    // Gaussian weights: g = exp(-x^2/(2*1.5^2)); g /= sum(g)  (matches jnp)
    float gw[11];
    {
        float s = 0.f;
        #pragma unroll
        for (int k = 0; k < 11; ++k) {
            float x = (float)(k - 5);
            gw[k] = expf(-x * x * (1.0f / 4.5f));
            s += gw[k];
        }
        float inv = 1.0f / s;
        #pragma unroll
        for (int k = 0; k < 11; ++k) gw[k] *= inv;
    }

    const float* rb = raw + (size_t)bc * (IMG * IMG);
    const float* db = dst + (size_t)bc * (IMG * IMG);

    // ---- Stage A: vertical conv. 304 tasks = 16 row-pairs x 19 x-groups. ----
    #pragma unroll 1
    for (int t = tid; t < 304; t += 256) {
        const int rp = t / 19;
        const int xg = t - rp * 19;
        int col0 = CB + tx0 + xg * 4;
        if (col0 > IMG - 4) col0 = IMG - 4;    // edge blocks: garbage cols unused
        const int row0 = CB + ty0 + rp * 2;

        float a0[4][4] = {{0.f}};   // moments for vs-row rp*2
        float a1[4][4] = {{0.f}};   // moments for vs-row rp*2+1
        #pragma unroll
        for (int k = 0; k < 12; ++k) {
            int r = row0 + k;
            if (r > IMG - 1) r = IMG - 1;      // bottom edge: rows unused
            const float4 va = *(const float4*)(rb + (size_t)r * IMG + col0);
            const float4 vc = *(const float4*)(db + (size_t)r * IMG + col0);
            const float R[4] = {va.x, va.y, va.z, va.w};
            const float D[4] = {vc.x, vc.y, vc.z, vc.w};
            float s2[4], p2[4];
            #pragma unroll
            for (int c = 0; c < 4; ++c) {
                const float u = R[c] + D[c];
                s2[c] = fmaf(R[c], R[c], D[c] * D[c]);   // r^2 + d^2
                p2[c] = u * u;                           // (r+d)^2
            }
            if (k < 11) {
                const float w = gw[k];
                #pragma unroll
                for (int c = 0; c < 4; ++c) {
                    a0[0][c] = fmaf(w, R[c],  a0[0][c]);
                    a0[1][c] = fmaf(w, D[c],  a0[1][c]);
                    a0[2][c] = fmaf(w, s2[c], a0[2][c]);
                    a0[3][c] = fmaf(w, p2[c], a0[3][c]);
                }
            }
            if (k >= 1) {
                const float w = gw[k - 1];
                #pragma unroll
                for (int c = 0; c < 4; ++c) {
                    a1[0][c] = fmaf(w, R[c],  a1[0][c]);
                    a1[1][c] = fmaf(w, D[c],  a1[1][c]);
                    a1[2][c] = fmaf(w, s2[c], a1[2][c]);
                    a1[3][c] = fmaf(w, p2[c], a1[3][c]);
                }
            }
        }
        #pragma unroll
        for (int f = 0; f < 4; ++f) {
            *(float4*)&vs[f][rp * 2 + 0][xg * 4] =
                make_float4(a0[f][0], a0[f][1], a0[f][2], a0[f][3]);
            *(float4*)&vs[f][rp * 2 + 1][xg * 4] =
                make_float4(a1[f][0], a1[f][1], a1[f][2], a1[f][3]);
        }
    }
    __syncthreads();

    // ---- Stage B: horizontal conv + SSIM. Thread = 8 cols x 1 row. ----
    // 5 ds_read_b128 per field -> 8 outputs (vs 4 reads -> 4 outputs before).
    const int xg  = tid & 7;
    const int row = tid >> 3;
    const int ox0 = tx0 + xg * 8;
    const int oy  = ty0 + row;

    float m[4][8];
    #pragma unroll
    for (int f = 0; f < 4; ++f) {
        const float4* vp = (const float4*)&vs[f][row][xg * 8];
        const float4 A = vp[0], B = vp[1], Cq = vp[2], Dq = vp[3], Eq = vp[4];
        const float win[20] = {A.x, A.y, A.z, A.w,  B.x, B.y, B.z, B.w,
                               Cq.x, Cq.y, Cq.z, Cq.w, Dq.x, Dq.y, Dq.z, Dq.w,
                               Eq.x, Eq.y, Eq.z, Eq.w};
        #pragma unroll
        for (int c = 0; c < 8; ++c) {
            float o = 0.f;
            #pragma unroll
            for (int k = 0; k < 11; ++k) o = fmaf(gw[k], win[c + k], o);
            m[f][c] = o;
        }
    }

    float ssum = 0.f;
    if (oy < OUTD) {
        #pragma unroll
        for (int c = 0; c < 8; ++c) {
            if (ox0 + c < OUTD) {
                const float mr  = m[0][c] * 255.0f;
                const float md  = m[1][c] * 255.0f;
                const float S2  = m[2][c] * 65025.0f;   // E[r^2]+E[d^2]
                const float P2  = m[3][c] * 65025.0f;   // E[(r+d)^2]
                const float mr2 = mr * mr, md2 = md * md, mpr = mr * md;
                // 2*cov = (P2 - S2) - 2*mr*md ; var_r+var_d = S2 - mr2 - md2
                const float num = (2.0f * mpr + C1F) *
                                  ((P2 - S2) - 2.0f * mpr + C2F);
                const float den = (mr2 + md2 + C1F) *
                                  ((S2 - mr2 - md2) + C2F);
                ssum += num / den;
            }
        }
    }

    // block reduction -> unique partial slot (no atomics)
    #pragma unroll
    for (int off = 32; off > 0; off >>= 1)
        ssum += __shfl_down(ssum, off, 64);
    const int lane = tid & 63, wv = tid >> 6;
    if (lane == 0) red[wv] = ssum;
    __syncthreads();
    if (tid == 0) {
        const float t = red[0] + red[1] + red[2] + red[3];
        partial[(size_t)b * SLOTS + (blockIdx.y * gridDim.x + blockIdx.x) * 3 + c3] = t;
    }
}

__global__ __launch_bounds__(128) void ssim_final(
        const float* __restrict__ partial, float* __restrict__ out) {
    __shared__ float red[2];
    const int b = blockIdx.x, tid = threadIdx.x;
    float s = 0.f;
    for (int i = tid; i < SLOTS; i += 128) s += partial[(size_t)b * SLOTS + i];
    #pragma unroll
    for (int off = 32; off > 0; off >>= 1) s += __shfl_down(s, off, 64);
    if ((tid & 63) == 0) red[tid >> 6] = s;
    __syncthreads();
    if (tid == 0) out[b] = (red[0] + red[1]) * (1.0f / NPIX);
}

extern "C" void kernel_launch(void* const* d_in, const int* in_sizes, int n_in,
                              void* d_out, int out_size, void* d_ws, size_t ws_size,
                              hipStream_t stream) {
    const float* raw = (const float*)d_in[0];
    const float* dst = (const float*)d_in[1];
    float* out     = (float*)d_out;
    float* partial = (float*)d_ws;   // 32*384 fp32, fully overwritten each call

    dim3 grid(XBLK, YBLK, 96);       // 8 x 16 x (32 batches * 3 channels)
    ssim_main<<<grid, 256, 0, stream>>>(raw, dst, partial);
    ssim_final<<<32, 128, 0, stream>>>(partial, out);
}